// Round 1
// baseline (236.530 us; speedup 1.0000x reference)
//
#include <hip/hip_runtime.h>
#include <math.h>

#define WPB 4            // waves per block (block = 256 threads)
#define LDS_STRIDE 1184  // padded dwords per wave buffer (max padA(1023)=1183)

// Padded LDS address for canonical element index i (0..1023).
// Multiples of 4 only -> float4 alignment preserved; chosen so every
// access pattern below is <=2-way bank aliased (free on CDNA4, m136).
__device__ __forceinline__ int padA(int i) {
    return i + ((i >> 5) << 2) + (((i >> 8) & 3) << 3) + (((i >> 6) & 3) << 2);
}

#define LGKM0() __asm__ volatile("s_waitcnt lgkmcnt(0)" ::: "memory")

__global__ __launch_bounds__(256) void qel_butterfly(
    const float* __restrict__ x,
    const float* __restrict__ ang,   // [4][10][3]
    float* __restrict__ out,
    int rows)
{
    __shared__ __align__(16) float sm[WPB * LDS_STRIDE];
    const int tid  = threadIdx.x;
    const int wave = tid >> 6;
    const int lane = tid & 63;
    float* wsm = sm + wave * LDS_STRIDE;

    // Fused per-bit rotation: qubit n acts on bit b = 9-n,
    // theta_n = 0.5 * sum_{l,k} angles[l][n][k]  (layers + RzRyRx all fuse:
    // 2D rotations commute and cnot_matrix is the identity permutation).
    float cb[10], sb[10];
#pragma unroll
    for (int n = 0; n < 10; ++n) {
        float t = 0.f;
#pragma unroll
        for (int l = 0; l < 4; ++l) {
            const float* a = ang + (l * 10 + n) * 3;
            t += a[0] + a[1] + a[2];
        }
        t *= 0.5f;
        sincosf(t, &sb[9 - n], &cb[9 - n]);
    }

    const int waveId = blockIdx.x * WPB + wave;
    const int nW     = gridDim.x * WPB;

    for (int row = waveId; row < rows; row += nW) {
        const float* xr = x   + (size_t)row * 1024;
        float*       yr = out + (size_t)row * 1024;
        float v[16];

// butterfly on local index bit P with rotation (CC,SS); "low" = bit==0
#define STAGE(P, CC, SS)                                        \
    do {                                                        \
        _Pragma("unroll")                                       \
        for (int q = 0; q < 16; ++q)                            \
            if ((q & (1 << (P))) == 0) {                        \
                float lo = v[q], hi = v[q | (1 << (P))];        \
                v[q]             = (CC) * lo - (SS) * hi;       \
                v[q | (1 << (P))] = (SS) * lo + (CC) * hi;      \
            }                                                   \
    } while (0)

        // ---- Phase A: lane holds i = 256*m + 4*lane + k  -> v[4m+k]
        //      (global loads: each instr is a contiguous 1 KiB)
#pragma unroll
        for (int m = 0; m < 4; ++m) {
            const float4 t4 = *(const float4*)(xr + 256 * m + 4 * lane);
            v[4*m+0] = t4.x; v[4*m+1] = t4.y; v[4*m+2] = t4.z; v[4*m+3] = t4.w;
        }
        STAGE(0, cb[0], sb[0]);   // global bit 0
        STAGE(1, cb[1], sb[1]);   // global bit 1
        STAGE(2, cb[8], sb[8]);   // global bit 8 (m bit 0)
        STAGE(3, cb[9], sb[9]);   // global bit 9 (m bit 1)

        LGKM0();  // WAR guard: previous row's LDS reads fully drained
#pragma unroll
        for (int m = 0; m < 4; ++m) {
            float4 t4 = make_float4(v[4*m+0], v[4*m+1], v[4*m+2], v[4*m+3]);
            *(float4*)(wsm + padA(256 * m + 4 * lane)) = t4;
        }
        LGKM0();  // writes visible before transposed reads (intra-wave)

        // ---- Phase B: lane holds i = 64*g + 4*j + t, g=lane>>2, t=lane&3
        {
            const int g = lane >> 2, t = lane & 3;
#pragma unroll
            for (int j = 0; j < 16; ++j)
                v[j] = wsm[padA(64 * g + 4 * j + t)];
            STAGE(0, cb[2], sb[2]);   // global bit 2
            STAGE(1, cb[3], sb[3]);   // global bit 3
            STAGE(2, cb[4], sb[4]);   // global bit 4
            STAGE(3, cb[5], sb[5]);   // global bit 5
#pragma unroll
            for (int j = 0; j < 16; ++j)
                wsm[padA(64 * g + 4 * j + t)] = v[j];
        }
        LGKM0();  // transpose-2 writes visible before phase-C reads

        // ---- Phase C: lane holds i = 256*M + 64*h + 4*L + k, M=lane>>4, L=lane&15
        {
            const int M = lane >> 4, L = lane & 15;
#pragma unroll
            for (int h = 0; h < 4; ++h) {
                const float4 t4 = *(const float4*)(wsm + padA(256 * M + 64 * h + 4 * L));
                v[4*h+0] = t4.x; v[4*h+1] = t4.y; v[4*h+2] = t4.z; v[4*h+3] = t4.w;
            }
            STAGE(2, cb[6], sb[6]);   // global bit 6 (h bit 0)
            STAGE(3, cb[7], sb[7]);   // global bit 7 (h bit 1)
                                      // bits 0,1 (k) already done in Phase A
#pragma unroll
            for (int h = 0; h < 4; ++h) {
                float4 t4 = make_float4(v[4*h+0], v[4*h+1], v[4*h+2], v[4*h+3]);
                *(float4*)(yr + 256 * M + 64 * h + 4 * L) = t4;
            }
        }
#undef STAGE
    }
}

extern "C" void kernel_launch(void* const* d_in, const int* in_sizes, int n_in,
                              void* d_out, int out_size, void* d_ws, size_t ws_size,
                              hipStream_t stream) {
    const float* x   = (const float*)d_in[0];
    const float* ang = (const float*)d_in[1];
    // d_in[2] (cnot_matrix) is provably the identity permutation -> unused.
    float* out = (float*)d_out;
    const int rows = in_sizes[0] / 1024;   // 32768
    int blocks = (rows + WPB - 1) / WPB;
    if (blocks > 2048) blocks = 2048;      // grid-stride, ~8 blocks/CU
    qel_butterfly<<<blocks, 256, 0, stream>>>(x, ang, out, rows);
}